// Round 11
// baseline (248.514 us; speedup 1.0000x reference)
//
#include <hip/hip_runtime.h>

// ---------------------------------------------------------------------------
// Single fused kernel. Every block redundantly computes the four 81-element
// coefficient tensors C[mi][q] in LDS (cheap, latency-overlapped across the
// 4 resident blocks/CU), then evaluates 4 patches/thread:
//   z_q = sum_a t01[a] * (sum_b C[a,b,q] * t23[b])
// with w_q = (1+cos x, sin x, 1-cos x) per qubit, t01 = w0 (x) w1,
// t23 = w2 (x) w3 (1/16 folded into C).
//
// Math: psi = D r (r real tensor product), final = U r with U = V*D;
// z_q = sum over ordered pairs (j,k) of r_j r_k M^q_jk,
// M^q_jk = sum_i sign_q(i) Re(conj(U_ij) U_ik), grouped by per-qubit
// signature m_q = j_q + k_q in {0,1,2}.
//
// Lessons baked in: NO runtime-indexed per-thread arrays (scratch, round 7);
// NO per-thread uniform global vector loads of C (load-path bound, rounds
// 1/6); single launch (no serial precompute kernel).
// ---------------------------------------------------------------------------
struct TF { float t01[9]; float t23[9]; };

__device__ __forceinline__ void build_t(const float4 a, TF& tf) {
  const float s0 = __sinf(a.x), c0 = __cosf(a.x);
  const float s1 = __sinf(a.y), c1 = __cosf(a.y);
  const float s2 = __sinf(a.z), c2 = __cosf(a.z);
  const float s3 = __sinf(a.w), c3 = __cosf(a.w);
  const float w0[3] = { 1.0f + c0, s0, 1.0f - c0 };
  const float w1[3] = { 1.0f + c1, s1, 1.0f - c1 };
  const float w2[3] = { 1.0f + c2, s2, 1.0f - c2 };
  const float w3[3] = { 1.0f + c3, s3, 1.0f - c3 };
#pragma unroll
  for (int i = 0; i < 3; ++i)
#pragma unroll
    for (int jj = 0; jj < 3; ++jj) {
      tf.t01[i * 3 + jj] = w0[i] * w1[jj];
      tf.t23[i * 3 + jj] = w2[i] * w3[jj];
    }
}

__global__ __launch_bounds__(256, 4) void qfused(const float4* __restrict__ x4,
                                                 const float* __restrict__ params,
                                                 float4* __restrict__ out,
                                                 int quarter) {
  __shared__ float colR[16][16];   // colR[j][i] = Re U_ij
  __shared__ float colI[16][16];
  __shared__ float Um[12][8];      // per-gate 2x2 complex
  __shared__ float4 S4[256];       // per ordered pair (j,k): 4 signed sums
  __shared__ float4 Cs[81];        // final coefficients (q0,q1,q2,q3)

  const int t = threadIdx.x;
  const int gid = blockIdx.x * 256 + t;

  // Issue the 4 input loads immediately; HBM latency hides under precompute.
  const float4 xa = x4[gid];
  const float4 xb = x4[gid + quarter];
  const float4 xc = x4[gid + 2 * quarter];
  const float4 xd = x4[gid + 3 * quarter];

  // ======== per-block coefficient precompute (same result every block) =====
  if (t < 16) {
#pragma unroll
    for (int i = 0; i < 16; ++i) { colR[t][i] = 0.0f; colI[t][i] = 0.0f; }
    int pc = __popc(t) & 3;
    colR[t][t] = (pc == 0) ? 1.0f : (pc == 2 ? -1.0f : 0.0f);
    colI[t][t] = (pc == 1) ? -1.0f : (pc == 3 ? 1.0f : 0.0f);
  }
  if (t < 12) {
    float phi = params[t * 3 + 0], th = params[t * 3 + 1], om = params[t * 3 + 2];
    float sa = __sinf(0.5f * (phi + om)), ca = __cosf(0.5f * (phi + om));
    float sb = __sinf(0.5f * (phi - om)), cb = __cosf(0.5f * (phi - om));
    float s2 = __sinf(0.5f * th),         c2 = __cosf(0.5f * th);
    Um[t][0] =  c2 * ca; Um[t][1] = -c2 * sa;   // m00 = e^{-i a} c
    Um[t][2] = -s2 * cb; Um[t][3] = -s2 * sb;   // m01 = -e^{+i b} s
    Um[t][4] =  s2 * cb; Um[t][5] = -s2 * sb;   // m10 =  e^{-i b} s
    Um[t][6] =  c2 * ca; Um[t][7] =  c2 * sa;   // m11 = e^{+i a} c
  }
  __syncthreads();

  const int j = t >> 3, p = t & 7;  // column j, pair p (valid for t<128)
  for (int l = 0; l < 3; ++l) {
    for (int q = 0; q < 4; ++q) {
      if (t < 128) {
        const int g = l * 4 + q;
        const int B = 3 - q, mask = 1 << B;           // qubit q = bit (3-q)
        const int i0 = ((p >> B) << (B + 1)) | (p & (mask - 1));
        const int i1 = i0 | mask;
        float a0r = colR[j][i0], a0i = colI[j][i0];
        float a1r = colR[j][i1], a1i = colI[j][i1];
        float m00r = Um[g][0], m00i = Um[g][1], m01r = Um[g][2], m01i = Um[g][3];
        float m10r = Um[g][4], m10i = Um[g][5], m11r = Um[g][6], m11i = Um[g][7];
        colR[j][i0] = m00r * a0r - m00i * a0i + m01r * a1r - m01i * a1i;
        colI[j][i0] = m00r * a0i + m00i * a0r + m01r * a1i + m01i * a1r;
        colR[j][i1] = m10r * a0r - m10i * a0i + m11r * a1r - m11i * a1i;
        colI[j][i1] = m10r * a0i + m10i * a0r + m11r * a1i + m11i * a1r;
      }
      __syncthreads();
    }
    for (int q = 0; q < 3; ++q) {
      if (t < 64) {
        const int jj = t >> 2, pp = t & 3;
        const int Bc = 3 - q, Bt = 2 - q;
        int fps[2], nf = 0;
        for (int b = 0; b < 4; ++b)
          if (b != Bc && b != Bt) fps[nf++] = b;
        const int i  = (1 << Bc) | ((pp & 1) << fps[0]) | (((pp >> 1) & 1) << fps[1]);
        const int i2 = i | (1 << Bt);
        float tr = colR[jj][i], ti = colI[jj][i];
        colR[jj][i] = colR[jj][i2]; colI[jj][i] = colI[jj][i2];
        colR[jj][i2] = tr;          colI[jj][i2] = ti;
      }
      __syncthreads();
    }
  }

  {  // Gram stage: thread t = ordered pair (j,k)
    const int jj = t >> 4, k = t & 15;
    float s0 = 0.f, s1 = 0.f, s2 = 0.f, s3 = 0.f;
#pragma unroll
    for (int i = 0; i < 16; ++i) {
      float pr = colR[jj][i] * colR[k][i] + colI[jj][i] * colI[k][i];
      s0 += ((i >> 3) & 1) ? -pr : pr;   // qubit 0 = bit 3
      s1 += ((i >> 2) & 1) ? -pr : pr;
      s2 += ((i >> 1) & 1) ? -pr : pr;
      s3 += ( i       & 1) ? -pr : pr;
    }
    S4[t] = make_float4(s0, s1, s2, s3);
  }
  __syncthreads();

  if (t < 81) {  // fold ordered pairs into the 81 signature bins
    const int m[4] = { t / 27, (t / 9) % 3, (t / 3) % 3, t % 3 };
    float a0 = 0.f, a1 = 0.f, a2 = 0.f, a3 = 0.f;
    for (int c = 0; c < 16; ++c) {
      int jj = 0, kk = 0; bool ok = true;
      for (int q = 0; q < 4; ++q) {
        int jb, kb;
        if (m[q] == 1) { jb = (c >> q) & 1; kb = 1 - jb; }
        else { jb = kb = (m[q] >> 1); if ((c >> q) & 1) ok = false; }
        jj |= jb << (3 - q); kk |= kb << (3 - q);
      }
      if (!ok) continue;
      float4 sv = S4[jj * 16 + kk];
      a0 += sv.x; a1 += sv.y; a2 += sv.z; a3 += sv.w;
    }
    Cs[t] = make_float4(a0 * 0.0625f, a1 * 0.0625f, a2 * 0.0625f, a3 * 0.0625f);
  }

  // ======== per-thread evaluation of 4 patches ============================
  TF tf[4];
  build_t(xa, tf[0]);
  build_t(xb, tf[1]);
  build_t(xc, tf[2]);
  build_t(xd, tf[3]);
  __syncthreads();            // Cs ready

  float z[4][4];
#pragma unroll
  for (int e = 0; e < 4; ++e)
#pragma unroll
    for (int q = 0; q < 4; ++q) z[e][q] = 0.f;

#pragma unroll
  for (int a = 0; a < 9; ++a) {          // FULL unroll: all indices static
    float v[4][4];
#pragma unroll
    for (int e = 0; e < 4; ++e)
#pragma unroll
      for (int q = 0; q < 4; ++q) v[e][q] = 0.f;
#pragma unroll
    for (int b = 0; b < 9; ++b) {
      const float4 c = Cs[a * 9 + b];    // LDS broadcast read (conflict-free)
#pragma unroll
      for (int e = 0; e < 4; ++e) {
        const float tb = tf[e].t23[b];
        v[e][0] = fmaf(c.x, tb, v[e][0]);
        v[e][1] = fmaf(c.y, tb, v[e][1]);
        v[e][2] = fmaf(c.z, tb, v[e][2]);
        v[e][3] = fmaf(c.w, tb, v[e][3]);
      }
    }
#pragma unroll
    for (int e = 0; e < 4; ++e) {
      const float ta = tf[e].t01[a];
      z[e][0] = fmaf(ta, v[e][0], z[e][0]);
      z[e][1] = fmaf(ta, v[e][1], z[e][1]);
      z[e][2] = fmaf(ta, v[e][2], z[e][2]);
      z[e][3] = fmaf(ta, v[e][3], z[e][3]);
    }
  }

  out[gid]               = make_float4(z[0][0], z[0][1], z[0][2], z[0][3]);
  out[gid + quarter]     = make_float4(z[1][0], z[1][1], z[1][2], z[1][3]);
  out[gid + 2 * quarter] = make_float4(z[2][0], z[2][1], z[2][2], z[2][3]);
  out[gid + 3 * quarter] = make_float4(z[3][0], z[3][1], z[3][2], z[3][3]);
}

extern "C" void kernel_launch(void* const* d_in, const int* in_sizes, int n_in,
                              void* d_out, int out_size, void* d_ws, size_t ws_size,
                              hipStream_t stream) {
  const float* x      = (const float*)d_in[0];
  const float* params = (const float*)d_in[1];

  const int M       = in_sizes[0] / 4;   // 1,048,576 patches
  const int quarter = M / 4;             // 262,144 threads, 4 elems each
  const int blocks  = quarter / 256;     // 1024 blocks -> 4 resident per CU
  qfused<<<blocks, 256, 0, stream>>>((const float4*)x, params,
                                     (float4*)d_out, quarter);
}

// Round 12
// 62.196 us; speedup vs baseline: 3.9957x; 3.9957x over previous
//
#include <hip/hip_runtime.h>

// ---------------------------------------------------------------------------
// Single fused kernel. Every block redundantly computes the four 81-element
// coefficient tensors C[mi][q] in LDS, then evaluates 2 patches/thread:
//   z_q = sum_a t01[a] * (sum_b C[a,b,q] * t23[b])
// with w_q = (1+cos x, sin x, 1-cos x) per qubit, t01 = w0 (x) w1,
// t23 = w2 (x) w3 (1/16 folded into C).
//
// Math: psi = D r (r real tensor product), final = U r with U = V*D;
// z_q = sum over ordered pairs (j,k) of r_j r_k M^q_jk,
// M^q_jk = sum_i sign_q(i) Re(conj(U_ij) U_ik), grouped by per-qubit
// signature m_q = j_q + k_q in {0,1,2}.
//
// Lessons baked in:
//  - round 7:  NO runtime-indexed per-thread arrays (-> scratch).
//  - round 11: NO __launch_bounds__ min-waves clause and NO 4-elem/thread:
//    the (256,4) bound capped VGPRs at 64, spilled ~100 floats/thread,
//    and turned the kernel into a 800 MB scratch-traffic bench (248 us,
//    VALUBusy 3.5%). 2 elem/thread (~80 live floats) fits registers.
//  - rounds 1/6: no per-thread uniform global vector loads of C.
// ---------------------------------------------------------------------------
struct TF { float t01[9]; float t23[9]; };

__device__ __forceinline__ void build_t(const float4 a, TF& tf) {
  const float s0 = __sinf(a.x), c0 = __cosf(a.x);
  const float s1 = __sinf(a.y), c1 = __cosf(a.y);
  const float s2 = __sinf(a.z), c2 = __cosf(a.z);
  const float s3 = __sinf(a.w), c3 = __cosf(a.w);
  const float w0[3] = { 1.0f + c0, s0, 1.0f - c0 };
  const float w1[3] = { 1.0f + c1, s1, 1.0f - c1 };
  const float w2[3] = { 1.0f + c2, s2, 1.0f - c2 };
  const float w3[3] = { 1.0f + c3, s3, 1.0f - c3 };
#pragma unroll
  for (int i = 0; i < 3; ++i)
#pragma unroll
    for (int jj = 0; jj < 3; ++jj) {
      tf.t01[i * 3 + jj] = w0[i] * w1[jj];
      tf.t23[i * 3 + jj] = w2[i] * w3[jj];
    }
}

__global__ __launch_bounds__(256) void qfused(const float4* __restrict__ x4,
                                              const float* __restrict__ params,
                                              float4* __restrict__ out,
                                              int half) {
  __shared__ float colR[16][16];   // colR[j][i] = Re U_ij
  __shared__ float colI[16][16];
  __shared__ float Um[12][8];      // per-gate 2x2 complex
  __shared__ float4 S4[256];       // per ordered pair (j,k): 4 signed sums
  __shared__ float4 Cs[81];        // final coefficients (q0,q1,q2,q3)

  const int t = threadIdx.x;
  const int gid = blockIdx.x * 256 + t;

  // Issue the 2 input loads immediately; HBM latency hides under precompute.
  const float4 xa = x4[gid];
  const float4 xb = x4[gid + half];

  // ======== per-block coefficient precompute (same result every block) =====
  if (t < 16) {
#pragma unroll
    for (int i = 0; i < 16; ++i) { colR[t][i] = 0.0f; colI[t][i] = 0.0f; }
    int pc = __popc(t) & 3;
    colR[t][t] = (pc == 0) ? 1.0f : (pc == 2 ? -1.0f : 0.0f);
    colI[t][t] = (pc == 1) ? -1.0f : (pc == 3 ? 1.0f : 0.0f);
  }
  if (t < 12) {
    float phi = params[t * 3 + 0], th = params[t * 3 + 1], om = params[t * 3 + 2];
    float sa = __sinf(0.5f * (phi + om)), ca = __cosf(0.5f * (phi + om));
    float sb = __sinf(0.5f * (phi - om)), cb = __cosf(0.5f * (phi - om));
    float s2 = __sinf(0.5f * th),         c2 = __cosf(0.5f * th);
    Um[t][0] =  c2 * ca; Um[t][1] = -c2 * sa;   // m00 = e^{-i a} c
    Um[t][2] = -s2 * cb; Um[t][3] = -s2 * sb;   // m01 = -e^{+i b} s
    Um[t][4] =  s2 * cb; Um[t][5] = -s2 * sb;   // m10 =  e^{-i b} s
    Um[t][6] =  c2 * ca; Um[t][7] =  c2 * sa;   // m11 = e^{+i a} c
  }
  __syncthreads();

  const int j = t >> 3, p = t & 7;  // column j, pair p (valid for t<128)
  for (int l = 0; l < 3; ++l) {
    for (int q = 0; q < 4; ++q) {
      if (t < 128) {
        const int g = l * 4 + q;
        const int B = 3 - q, mask = 1 << B;           // qubit q = bit (3-q)
        const int i0 = ((p >> B) << (B + 1)) | (p & (mask - 1));
        const int i1 = i0 | mask;
        float a0r = colR[j][i0], a0i = colI[j][i0];
        float a1r = colR[j][i1], a1i = colI[j][i1];
        float m00r = Um[g][0], m00i = Um[g][1], m01r = Um[g][2], m01i = Um[g][3];
        float m10r = Um[g][4], m10i = Um[g][5], m11r = Um[g][6], m11i = Um[g][7];
        colR[j][i0] = m00r * a0r - m00i * a0i + m01r * a1r - m01i * a1i;
        colI[j][i0] = m00r * a0i + m00i * a0r + m01r * a1i + m01i * a1r;
        colR[j][i1] = m10r * a0r - m10i * a0i + m11r * a1r - m11i * a1i;
        colI[j][i1] = m10r * a0i + m10i * a0r + m11r * a1i + m11i * a1r;
      }
      __syncthreads();
    }
    for (int q = 0; q < 3; ++q) {
      if (t < 64) {
        const int jj = t >> 2, pp = t & 3;
        const int Bc = 3 - q, Bt = 2 - q;
        int fps[2], nf = 0;
        for (int b = 0; b < 4; ++b)
          if (b != Bc && b != Bt) fps[nf++] = b;
        const int i  = (1 << Bc) | ((pp & 1) << fps[0]) | (((pp >> 1) & 1) << fps[1]);
        const int i2 = i | (1 << Bt);
        float tr = colR[jj][i], ti = colI[jj][i];
        colR[jj][i] = colR[jj][i2]; colI[jj][i] = colI[jj][i2];
        colR[jj][i2] = tr;          colI[jj][i2] = ti;
      }
      __syncthreads();
    }
  }

  {  // Gram stage: thread t = ordered pair (j,k)
    const int jj = t >> 4, k = t & 15;
    float s0 = 0.f, s1 = 0.f, s2 = 0.f, s3 = 0.f;
#pragma unroll
    for (int i = 0; i < 16; ++i) {
      float pr = colR[jj][i] * colR[k][i] + colI[jj][i] * colI[k][i];
      s0 += ((i >> 3) & 1) ? -pr : pr;   // qubit 0 = bit 3
      s1 += ((i >> 2) & 1) ? -pr : pr;
      s2 += ((i >> 1) & 1) ? -pr : pr;
      s3 += ( i       & 1) ? -pr : pr;
    }
    S4[t] = make_float4(s0, s1, s2, s3);
  }
  __syncthreads();

  if (t < 81) {  // fold ordered pairs into the 81 signature bins
    const int m[4] = { t / 27, (t / 9) % 3, (t / 3) % 3, t % 3 };
    float a0 = 0.f, a1 = 0.f, a2 = 0.f, a3 = 0.f;
    for (int c = 0; c < 16; ++c) {
      int jj = 0, kk = 0; bool ok = true;
      for (int q = 0; q < 4; ++q) {
        int jb, kb;
        if (m[q] == 1) { jb = (c >> q) & 1; kb = 1 - jb; }
        else { jb = kb = (m[q] >> 1); if ((c >> q) & 1) ok = false; }
        jj |= jb << (3 - q); kk |= kb << (3 - q);
      }
      if (!ok) continue;
      float4 sv = S4[jj * 16 + kk];
      a0 += sv.x; a1 += sv.y; a2 += sv.z; a3 += sv.w;
    }
    Cs[t] = make_float4(a0 * 0.0625f, a1 * 0.0625f, a2 * 0.0625f, a3 * 0.0625f);
  }

  // ======== per-thread evaluation of 2 patches ============================
  TF tfA, tfB;
  build_t(xa, tfA);
  build_t(xb, tfB);
  __syncthreads();            // Cs ready

  float zA0 = 0.f, zA1 = 0.f, zA2 = 0.f, zA3 = 0.f;
  float zB0 = 0.f, zB1 = 0.f, zB2 = 0.f, zB3 = 0.f;

#pragma unroll
  for (int a = 0; a < 9; ++a) {          // FULL unroll: all indices static
    float vA0 = 0.f, vA1 = 0.f, vA2 = 0.f, vA3 = 0.f;
    float vB0 = 0.f, vB1 = 0.f, vB2 = 0.f, vB3 = 0.f;
#pragma unroll
    for (int b = 0; b < 9; ++b) {
      const float4 c = Cs[a * 9 + b];    // LDS broadcast read (conflict-free)
      const float tbA = tfA.t23[b];
      const float tbB = tfB.t23[b];
      vA0 = fmaf(c.x, tbA, vA0); vA1 = fmaf(c.y, tbA, vA1);
      vA2 = fmaf(c.z, tbA, vA2); vA3 = fmaf(c.w, tbA, vA3);
      vB0 = fmaf(c.x, tbB, vB0); vB1 = fmaf(c.y, tbB, vB1);
      vB2 = fmaf(c.z, tbB, vB2); vB3 = fmaf(c.w, tbB, vB3);
    }
    const float taA = tfA.t01[a];
    const float taB = tfB.t01[a];
    zA0 = fmaf(taA, vA0, zA0); zA1 = fmaf(taA, vA1, zA1);
    zA2 = fmaf(taA, vA2, zA2); zA3 = fmaf(taA, vA3, zA3);
    zB0 = fmaf(taB, vB0, zB0); zB1 = fmaf(taB, vB1, zB1);
    zB2 = fmaf(taB, vB2, zB2); zB3 = fmaf(taB, vB3, zB3);
  }

  out[gid]        = make_float4(zA0, zA1, zA2, zA3);
  out[gid + half] = make_float4(zB0, zB1, zB2, zB3);
}

extern "C" void kernel_launch(void* const* d_in, const int* in_sizes, int n_in,
                              void* d_out, int out_size, void* d_ws, size_t ws_size,
                              hipStream_t stream) {
  const float* x      = (const float*)d_in[0];
  const float* params = (const float*)d_in[1];

  const int M      = in_sizes[0] / 4;   // 1,048,576 patches
  const int half   = M / 2;             // 524,288 threads, 2 elems each
  const int blocks = half / 256;        // 2048 blocks
  qfused<<<blocks, 256, 0, stream>>>((const float4*)x, params,
                                     (float4*)d_out, half);
}

// Round 13
// 35.366 us; speedup vs baseline: 7.0270x; 1.7587x over previous
//
#include <hip/hip_runtime.h>

// ---------------------------------------------------------------------------
// Two kernels (round-12 lesson: the barrier-laden precompute must run ONCE,
// not per block -- fusing it into 2048 blocks was 62 us of barrier latency).
//
// qprecomp (1 block): builds the four 81-element coefficient tensors C[mi][q]
//   such that z_q = sum_mi C[mi][q] * prod_q w_q[m_q],
//   w_q = (1+cos x_q, sin x_q, 1-cos x_q), 1/16 folded into C.
//   psi = D r (r real tensor product), final = U r with U = V*D;
//   M^q_jk = sum_i sign_q(i) Re(conj(U_ij) U_ik), grouped by signature
//   m_q = j_q + k_q in {0,1,2}.
//
// qeval (2048 blocks): stages C into LDS once per block (coalesced, 1
//   barrier), then 2 patches/thread, fully static unroll, LDS broadcast
//   reads (conflict-free). Round-11 lesson: no launch_bounds min-waves
//   clause, 2 elem/thread keeps ~90 live floats -> no spill (VGPR 148).
//   Rounds-1/6 lesson: NO per-thread 81x uniform global_load_dwordx4.
// ---------------------------------------------------------------------------
__global__ __launch_bounds__(256) void qprecomp(const float* __restrict__ params,
                                                float* __restrict__ C) {
  __shared__ float colR[16][16];   // colR[j][i] = Re U_ij
  __shared__ float colI[16][16];
  __shared__ float Um[12][8];      // per-gate 2x2 complex
  __shared__ float4 S4[256];       // per ordered pair (j,k): 4 signed sums
  const int t = threadIdx.x;

  if (t < 16) {
#pragma unroll
    for (int i = 0; i < 16; ++i) { colR[t][i] = 0.0f; colI[t][i] = 0.0f; }
    int pc = __popc(t) & 3;
    colR[t][t] = (pc == 0) ? 1.0f : (pc == 2 ? -1.0f : 0.0f);
    colI[t][t] = (pc == 1) ? -1.0f : (pc == 3 ? 1.0f : 0.0f);
  }
  if (t < 12) {
    float phi = params[t * 3 + 0], th = params[t * 3 + 1], om = params[t * 3 + 2];
    float sa = __sinf(0.5f * (phi + om)), ca = __cosf(0.5f * (phi + om));
    float sb = __sinf(0.5f * (phi - om)), cb = __cosf(0.5f * (phi - om));
    float s2 = __sinf(0.5f * th),         c2 = __cosf(0.5f * th);
    Um[t][0] =  c2 * ca; Um[t][1] = -c2 * sa;   // m00 = e^{-i a} c
    Um[t][2] = -s2 * cb; Um[t][3] = -s2 * sb;   // m01 = -e^{+i b} s
    Um[t][4] =  s2 * cb; Um[t][5] = -s2 * sb;   // m10 =  e^{-i b} s
    Um[t][6] =  c2 * ca; Um[t][7] =  c2 * sa;   // m11 = e^{+i a} c
  }
  __syncthreads();

  const int j = t >> 3, p = t & 7;  // column j, pair p (valid for t<128)
  for (int l = 0; l < 3; ++l) {
    for (int q = 0; q < 4; ++q) {
      if (t < 128) {
        const int g = l * 4 + q;
        const int B = 3 - q, mask = 1 << B;           // qubit q = bit (3-q)
        const int i0 = ((p >> B) << (B + 1)) | (p & (mask - 1));
        const int i1 = i0 | mask;
        float a0r = colR[j][i0], a0i = colI[j][i0];
        float a1r = colR[j][i1], a1i = colI[j][i1];
        float m00r = Um[g][0], m00i = Um[g][1], m01r = Um[g][2], m01i = Um[g][3];
        float m10r = Um[g][4], m10i = Um[g][5], m11r = Um[g][6], m11i = Um[g][7];
        colR[j][i0] = m00r * a0r - m00i * a0i + m01r * a1r - m01i * a1i;
        colI[j][i0] = m00r * a0i + m00i * a0r + m01r * a1i + m01i * a1r;
        colR[j][i1] = m10r * a0r - m10i * a0i + m11r * a1r - m11i * a1i;
        colI[j][i1] = m10r * a0i + m10i * a0r + m11r * a1i + m11i * a1r;
      }
      __syncthreads();
    }
    for (int q = 0; q < 3; ++q) {
      if (t < 64) {
        const int jj = t >> 2, pp = t & 3;
        const int Bc = 3 - q, Bt = 2 - q;
        int fps[2], nf = 0;
        for (int b = 0; b < 4; ++b)
          if (b != Bc && b != Bt) fps[nf++] = b;
        const int i  = (1 << Bc) | ((pp & 1) << fps[0]) | (((pp >> 1) & 1) << fps[1]);
        const int i2 = i | (1 << Bt);
        float tr = colR[jj][i], ti = colI[jj][i];
        colR[jj][i] = colR[jj][i2]; colI[jj][i] = colI[jj][i2];
        colR[jj][i2] = tr;          colI[jj][i2] = ti;
      }
      __syncthreads();
    }
  }

  {  // Gram stage: thread t = ordered pair (j,k)
    const int jj = t >> 4, k = t & 15;
    float s0 = 0.f, s1 = 0.f, s2 = 0.f, s3 = 0.f;
#pragma unroll
    for (int i = 0; i < 16; ++i) {
      float pr = colR[jj][i] * colR[k][i] + colI[jj][i] * colI[k][i];
      s0 += ((i >> 3) & 1) ? -pr : pr;   // qubit 0 = bit 3
      s1 += ((i >> 2) & 1) ? -pr : pr;
      s2 += ((i >> 1) & 1) ? -pr : pr;
      s3 += ( i       & 1) ? -pr : pr;
    }
    S4[t] = make_float4(s0, s1, s2, s3);
  }
  __syncthreads();

  if (t < 81) {  // fold ordered pairs into the 81 signature bins
    const int m[4] = { t / 27, (t / 9) % 3, (t / 3) % 3, t % 3 };
    float a0 = 0.f, a1 = 0.f, a2 = 0.f, a3 = 0.f;
    for (int c = 0; c < 16; ++c) {
      int jj = 0, kk = 0; bool ok = true;
      for (int q = 0; q < 4; ++q) {
        int jb, kb;
        if (m[q] == 1) { jb = (c >> q) & 1; kb = 1 - jb; }
        else { jb = kb = (m[q] >> 1); if ((c >> q) & 1) ok = false; }
        jj |= jb << (3 - q); kk |= kb << (3 - q);
      }
      if (!ok) continue;
      float4 sv = S4[jj * 16 + kk];
      a0 += sv.x; a1 += sv.y; a2 += sv.z; a3 += sv.w;
    }
    C[t * 4 + 0] = a0 * 0.0625f;
    C[t * 4 + 1] = a1 * 0.0625f;
    C[t * 4 + 2] = a2 * 0.0625f;
    C[t * 4 + 3] = a3 * 0.0625f;
  }
}

// ---------------------------------------------------------------------------
struct TF { float t01[9]; float t23[9]; };

__device__ __forceinline__ void build_t(const float4 a, TF& tf) {
  const float s0 = __sinf(a.x), c0 = __cosf(a.x);
  const float s1 = __sinf(a.y), c1 = __cosf(a.y);
  const float s2 = __sinf(a.z), c2 = __cosf(a.z);
  const float s3 = __sinf(a.w), c3 = __cosf(a.w);
  const float w0[3] = { 1.0f + c0, s0, 1.0f - c0 };
  const float w1[3] = { 1.0f + c1, s1, 1.0f - c1 };
  const float w2[3] = { 1.0f + c2, s2, 1.0f - c2 };
  const float w3[3] = { 1.0f + c3, s3, 1.0f - c3 };
#pragma unroll
  for (int i = 0; i < 3; ++i)
#pragma unroll
    for (int jj = 0; jj < 3; ++jj) {
      tf.t01[i * 3 + jj] = w0[i] * w1[jj];
      tf.t23[i * 3 + jj] = w2[i] * w3[jj];
    }
}

__global__ __launch_bounds__(256) void qeval(const float4* __restrict__ x4,
                                             const float4* __restrict__ C4,
                                             float4* __restrict__ out,
                                             int half) {
  __shared__ float4 Cs[81];
  const int t = threadIdx.x;
  if (t < 81) Cs[t] = C4[t];          // one coalesced stage per block

  const int gid = blockIdx.x * 256 + t;
  const float4 xa = x4[gid];
  const float4 xb = x4[gid + half];

  TF tfA, tfB;
  build_t(xa, tfA);                   // trig overlaps the staging latency
  build_t(xb, tfB);
  __syncthreads();                    // Cs ready

  float zA0 = 0.f, zA1 = 0.f, zA2 = 0.f, zA3 = 0.f;
  float zB0 = 0.f, zB1 = 0.f, zB2 = 0.f, zB3 = 0.f;

#pragma unroll
  for (int a = 0; a < 9; ++a) {       // FULL unroll: all indices static
    float vA0 = 0.f, vA1 = 0.f, vA2 = 0.f, vA3 = 0.f;
    float vB0 = 0.f, vB1 = 0.f, vB2 = 0.f, vB3 = 0.f;
#pragma unroll
    for (int b = 0; b < 9; ++b) {
      const float4 c = Cs[a * 9 + b]; // LDS broadcast read (conflict-free)
      const float tbA = tfA.t23[b];
      const float tbB = tfB.t23[b];
      vA0 = fmaf(c.x, tbA, vA0); vA1 = fmaf(c.y, tbA, vA1);
      vA2 = fmaf(c.z, tbA, vA2); vA3 = fmaf(c.w, tbA, vA3);
      vB0 = fmaf(c.x, tbB, vB0); vB1 = fmaf(c.y, tbB, vB1);
      vB2 = fmaf(c.z, tbB, vB2); vB3 = fmaf(c.w, tbB, vB3);
    }
    const float taA = tfA.t01[a];
    const float taB = tfB.t01[a];
    zA0 = fmaf(taA, vA0, zA0); zA1 = fmaf(taA, vA1, zA1);
    zA2 = fmaf(taA, vA2, zA2); zA3 = fmaf(taA, vA3, zA3);
    zB0 = fmaf(taB, vB0, zB0); zB1 = fmaf(taB, vB1, zB1);
    zB2 = fmaf(taB, vB2, zB2); zB3 = fmaf(taB, vB3, zB3);
  }

  out[gid]        = make_float4(zA0, zA1, zA2, zA3);
  out[gid + half] = make_float4(zB0, zB1, zB2, zB3);
}

extern "C" void kernel_launch(void* const* d_in, const int* in_sizes, int n_in,
                              void* d_out, int out_size, void* d_ws, size_t ws_size,
                              hipStream_t stream) {
  const float* x      = (const float*)d_in[0];
  const float* params = (const float*)d_in[1];
  float* C = (float*)d_ws;            // 324 floats of scratch

  qprecomp<<<1, 256, 0, stream>>>(params, C);

  const int M      = in_sizes[0] / 4; // 1,048,576 patches
  const int half   = M / 2;           // 524,288 threads, 2 elems each
  const int blocks = half / 256;      // 2048 blocks
  qeval<<<blocks, 256, 0, stream>>>((const float4*)x, (const float4*)C,
                                    (float4*)d_out, half);
}

// Round 14
// 23.552 us; speedup vs baseline: 10.5515x; 1.5016x over previous
//
#include <hip/hip_runtime.h>

// ---------------------------------------------------------------------------
// Two kernels. qprecomp (1 block) builds the four 81-element coefficient
// tensors C[mi][q]:  z_q = sum_mi C[mi][q] * prod_q w_q[m_q],
// w_q = (1+cos x_q, sin x_q, 1-cos x_q), 1/16 folded into C.
// psi = D r (real tensor-product r), final = U r, U = V*D;
// M^q_jk = sum_i sign_q(i) Re(conj(U_ij) U_ik), binned by per-qubit
// signature m_q = j_q + k_q in {0,1,2}.
//
// qeval: 4 patches/thread, C read through the GLOBAL __restrict__ const
// pointer with compile-time-constant indices -> compiler scalarizes to
// s_load + v_fma with SGPR operand (scalar-cache-hot, zero VGPR cost).
// Lessons: LDS staging of C is SLOWER (r13: ds_read latency chain, 35 us);
// runtime-indexed arrays -> scratch (r7); __launch_bounds__ min-waves
// clause -> forced spill (r11); eval is latency-bound on C access, so
// amortize each C value over 4 elements (16 FMA/value).
// ---------------------------------------------------------------------------
__global__ __launch_bounds__(256) void qprecomp(const float* __restrict__ params,
                                                float* __restrict__ C) {
  __shared__ float colR[16][16];   // colR[j][i] = Re U_ij
  __shared__ float colI[16][16];
  __shared__ float Um[12][8];      // per-gate 2x2 complex
  __shared__ float4 S4[256];       // per ordered pair (j,k): 4 signed sums
  const int t = threadIdx.x;

  if (t < 16) {
#pragma unroll
    for (int i = 0; i < 16; ++i) { colR[t][i] = 0.0f; colI[t][i] = 0.0f; }
    int pc = __popc(t) & 3;
    colR[t][t] = (pc == 0) ? 1.0f : (pc == 2 ? -1.0f : 0.0f);
    colI[t][t] = (pc == 1) ? -1.0f : (pc == 3 ? 1.0f : 0.0f);
  }
  if (t < 12) {
    float phi = params[t * 3 + 0], th = params[t * 3 + 1], om = params[t * 3 + 2];
    float sa = __sinf(0.5f * (phi + om)), ca = __cosf(0.5f * (phi + om));
    float sb = __sinf(0.5f * (phi - om)), cb = __cosf(0.5f * (phi - om));
    float s2 = __sinf(0.5f * th),         c2 = __cosf(0.5f * th);
    Um[t][0] =  c2 * ca; Um[t][1] = -c2 * sa;   // m00 = e^{-i a} c
    Um[t][2] = -s2 * cb; Um[t][3] = -s2 * sb;   // m01 = -e^{+i b} s
    Um[t][4] =  s2 * cb; Um[t][5] = -s2 * sb;   // m10 =  e^{-i b} s
    Um[t][6] =  c2 * ca; Um[t][7] =  c2 * sa;   // m11 = e^{+i a} c
  }
  __syncthreads();

  const int j = t >> 3, p = t & 7;  // column j, pair p (valid for t<128)
  for (int l = 0; l < 3; ++l) {
    for (int q = 0; q < 4; ++q) {
      if (t < 128) {
        const int g = l * 4 + q;
        const int B = 3 - q, mask = 1 << B;           // qubit q = bit (3-q)
        const int i0 = ((p >> B) << (B + 1)) | (p & (mask - 1));
        const int i1 = i0 | mask;
        float a0r = colR[j][i0], a0i = colI[j][i0];
        float a1r = colR[j][i1], a1i = colI[j][i1];
        float m00r = Um[g][0], m00i = Um[g][1], m01r = Um[g][2], m01i = Um[g][3];
        float m10r = Um[g][4], m10i = Um[g][5], m11r = Um[g][6], m11i = Um[g][7];
        colR[j][i0] = m00r * a0r - m00i * a0i + m01r * a1r - m01i * a1i;
        colI[j][i0] = m00r * a0i + m00i * a0r + m01r * a1i + m01i * a1r;
        colR[j][i1] = m10r * a0r - m10i * a0i + m11r * a1r - m11i * a1i;
        colI[j][i1] = m10r * a0i + m10i * a0r + m11r * a1i + m11i * a1r;
      }
      __syncthreads();
    }
    for (int q = 0; q < 3; ++q) {
      if (t < 64) {
        const int jj = t >> 2, pp = t & 3;
        const int Bc = 3 - q, Bt = 2 - q;
        int fps[2], nf = 0;
        for (int b = 0; b < 4; ++b)
          if (b != Bc && b != Bt) fps[nf++] = b;
        const int i  = (1 << Bc) | ((pp & 1) << fps[0]) | (((pp >> 1) & 1) << fps[1]);
        const int i2 = i | (1 << Bt);
        float tr = colR[jj][i], ti = colI[jj][i];
        colR[jj][i] = colR[jj][i2]; colI[jj][i] = colI[jj][i2];
        colR[jj][i2] = tr;          colI[jj][i2] = ti;
      }
      __syncthreads();
    }
  }

  {  // Gram stage: thread t = ordered pair (j,k)
    const int jj = t >> 4, k = t & 15;
    float s0 = 0.f, s1 = 0.f, s2 = 0.f, s3 = 0.f;
#pragma unroll
    for (int i = 0; i < 16; ++i) {
      float pr = colR[jj][i] * colR[k][i] + colI[jj][i] * colI[k][i];
      s0 += ((i >> 3) & 1) ? -pr : pr;   // qubit 0 = bit 3
      s1 += ((i >> 2) & 1) ? -pr : pr;
      s2 += ((i >> 1) & 1) ? -pr : pr;
      s3 += ( i       & 1) ? -pr : pr;
    }
    S4[t] = make_float4(s0, s1, s2, s3);
  }
  __syncthreads();

  if (t < 81) {  // fold ordered pairs into the 81 signature bins
    const int m[4] = { t / 27, (t / 9) % 3, (t / 3) % 3, t % 3 };
    float a0 = 0.f, a1 = 0.f, a2 = 0.f, a3 = 0.f;
    for (int c = 0; c < 16; ++c) {
      int jj = 0, kk = 0; bool ok = true;
      for (int q = 0; q < 4; ++q) {
        int jb, kb;
        if (m[q] == 1) { jb = (c >> q) & 1; kb = 1 - jb; }
        else { jb = kb = (m[q] >> 1); if ((c >> q) & 1) ok = false; }
        jj |= jb << (3 - q); kk |= kb << (3 - q);
      }
      if (!ok) continue;
      float4 sv = S4[jj * 16 + kk];
      a0 += sv.x; a1 += sv.y; a2 += sv.z; a3 += sv.w;
    }
    C[t * 4 + 0] = a0 * 0.0625f;
    C[t * 4 + 1] = a1 * 0.0625f;
    C[t * 4 + 2] = a2 * 0.0625f;
    C[t * 4 + 3] = a3 * 0.0625f;
  }
}

// ---------------------------------------------------------------------------
struct TF { float t01[9]; float t23[9]; };

__device__ __forceinline__ void build_t(const float4 a, TF& tf) {
  const float s0 = __sinf(a.x), c0 = __cosf(a.x);
  const float s1 = __sinf(a.y), c1 = __cosf(a.y);
  const float s2 = __sinf(a.z), c2 = __cosf(a.z);
  const float s3 = __sinf(a.w), c3 = __cosf(a.w);
  const float w0[3] = { 1.0f + c0, s0, 1.0f - c0 };
  const float w1[3] = { 1.0f + c1, s1, 1.0f - c1 };
  const float w2[3] = { 1.0f + c2, s2, 1.0f - c2 };
  const float w3[3] = { 1.0f + c3, s3, 1.0f - c3 };
#pragma unroll
  for (int i = 0; i < 3; ++i)
#pragma unroll
    for (int jj = 0; jj < 3; ++jj) {
      tf.t01[i * 3 + jj] = w0[i] * w1[jj];
      tf.t23[i * 3 + jj] = w2[i] * w3[jj];
    }
}

__global__ __launch_bounds__(256) void qeval(const float4* __restrict__ x4,
                                             const float4* __restrict__ C4,
                                             float4* __restrict__ out,
                                             int quarter) {
  const int gid = blockIdx.x * 256 + threadIdx.x;

  const float4 xa = x4[gid];
  const float4 xb = x4[gid + quarter];
  const float4 xc = x4[gid + 2 * quarter];
  const float4 xd = x4[gid + 3 * quarter];

  TF tfA, tfB, tfC, tfD;
  build_t(xa, tfA);
  build_t(xb, tfB);
  build_t(xc, tfC);
  build_t(xd, tfD);

  float zA0 = 0.f, zA1 = 0.f, zA2 = 0.f, zA3 = 0.f;
  float zB0 = 0.f, zB1 = 0.f, zB2 = 0.f, zB3 = 0.f;
  float zC0 = 0.f, zC1 = 0.f, zC2 = 0.f, zC3 = 0.f;
  float zD0 = 0.f, zD1 = 0.f, zD2 = 0.f, zD3 = 0.f;

#pragma unroll
  for (int a = 0; a < 9; ++a) {        // FULL unroll: every index static
    float vA0 = 0.f, vA1 = 0.f, vA2 = 0.f, vA3 = 0.f;
    float vB0 = 0.f, vB1 = 0.f, vB2 = 0.f, vB3 = 0.f;
    float vC0 = 0.f, vC1 = 0.f, vC2 = 0.f, vC3 = 0.f;
    float vD0 = 0.f, vD1 = 0.f, vD2 = 0.f, vD3 = 0.f;
#pragma unroll
    for (int b = 0; b < 9; ++b) {
      // Uniform address, compile-time index -> scalarized s_load; the FMAs
      // consume the SGPR operand directly (16 FMA per coefficient value).
      const float4 c = C4[a * 9 + b];
      const float tbA = tfA.t23[b], tbB = tfB.t23[b];
      const float tbC = tfC.t23[b], tbD = tfD.t23[b];
      vA0 = fmaf(c.x, tbA, vA0); vA1 = fmaf(c.y, tbA, vA1);
      vA2 = fmaf(c.z, tbA, vA2); vA3 = fmaf(c.w, tbA, vA3);
      vB0 = fmaf(c.x, tbB, vB0); vB1 = fmaf(c.y, tbB, vB1);
      vB2 = fmaf(c.z, tbB, vB2); vB3 = fmaf(c.w, tbB, vB3);
      vC0 = fmaf(c.x, tbC, vC0); vC1 = fmaf(c.y, tbC, vC1);
      vC2 = fmaf(c.z, tbC, vC2); vC3 = fmaf(c.w, tbC, vC3);
      vD0 = fmaf(c.x, tbD, vD0); vD1 = fmaf(c.y, tbD, vD1);
      vD2 = fmaf(c.z, tbD, vD2); vD3 = fmaf(c.w, tbD, vD3);
    }
    const float taA = tfA.t01[a], taB = tfB.t01[a];
    const float taC = tfC.t01[a], taD = tfD.t01[a];
    zA0 = fmaf(taA, vA0, zA0); zA1 = fmaf(taA, vA1, zA1);
    zA2 = fmaf(taA, vA2, zA2); zA3 = fmaf(taA, vA3, zA3);
    zB0 = fmaf(taB, vB0, zB0); zB1 = fmaf(taB, vB1, zB1);
    zB2 = fmaf(taB, vB2, zB2); zB3 = fmaf(taB, vB3, zB3);
    zC0 = fmaf(taC, vC0, zC0); zC1 = fmaf(taC, vC1, zC1);
    zC2 = fmaf(taC, vC2, zC2); zC3 = fmaf(taC, vC3, zC3);
    zD0 = fmaf(taD, vD0, zD0); zD1 = fmaf(taD, vD1, zD1);
    zD2 = fmaf(taD, vD2, zD2); zD3 = fmaf(taD, vD3, zD3);
  }

  out[gid]               = make_float4(zA0, zA1, zA2, zA3);
  out[gid + quarter]     = make_float4(zB0, zB1, zB2, zB3);
  out[gid + 2 * quarter] = make_float4(zC0, zC1, zC2, zC3);
  out[gid + 3 * quarter] = make_float4(zD0, zD1, zD2, zD3);
}

extern "C" void kernel_launch(void* const* d_in, const int* in_sizes, int n_in,
                              void* d_out, int out_size, void* d_ws, size_t ws_size,
                              hipStream_t stream) {
  const float* x      = (const float*)d_in[0];
  const float* params = (const float*)d_in[1];
  float* C = (float*)d_ws;              // 324 floats of scratch

  qprecomp<<<1, 256, 0, stream>>>(params, C);

  const int M       = in_sizes[0] / 4;  // 1,048,576 patches
  const int quarter = M / 4;            // 262,144 threads, 4 elems each
  const int blocks  = quarter / 256;    // 1024 blocks
  qeval<<<blocks, 256, 0, stream>>>((const float4*)x, (const float4*)C,
                                    (float4*)d_out, quarter);
}